// Round 12
// baseline (371.512 us; speedup 1.0000x reference)
//
#include <hip/hip_runtime.h>
#include <hip/hip_bf16.h>

#define DM 1024
#define NH 16
#define DKK 64
#define SL 2048
#define NBATCH 2
#define NR (NBATCH*SL)   // 4096 rows

typedef __attribute__((ext_vector_type(8))) __bf16 bf16x8;
typedef __attribute__((ext_vector_type(4))) float f32x4;
using bf16 = __hip_bfloat16;

// Q pre-scale: 1/sqrt(64) * log2(e), so exp2(s) == exp(s_orig/8)
#define QSCALE 0.18033688011112042f

// ---------------- merged fp32 -> bf16 converts: y=0 -> x, y=1..4 -> weights ----------------
__global__ __launch_bounds__(256) void cvt5_kernel(
    const float* __restrict__ sx, const float* __restrict__ s1,
    const float* __restrict__ s2, const float* __restrict__ s3, const float* __restrict__ s4,
    bf16* __restrict__ dx, bf16* __restrict__ d1,
    bf16* __restrict__ d2, bf16* __restrict__ d3, bf16* __restrict__ d4) {
  const int z = blockIdx.y;
  const float* src = (z == 0) ? sx : (z == 1) ? s1 : (z == 2) ? s2 : (z == 3) ? s3 : s4;
  bf16* dst = (z == 0) ? dx : (z == 1) ? d1 : (z == 2) ? d2 : (z == 3) ? d3 : d4;
  const int n4 = (z == 0) ? (NR * DM / 4) : (DM * DM / 4);
  int stride = gridDim.x * blockDim.x;
  for (int i = blockIdx.x * blockDim.x + threadIdx.x; i < n4; i += stride) {
    float4 v = ((const float4*)src)[i];
    union { bf16 h[4]; ushort4 u; } un;
    un.h[0] = __float2bfloat16(v.x);
    un.h[1] = __float2bfloat16(v.y);
    un.h[2] = __float2bfloat16(v.z);
    un.h[3] = __float2bfloat16(v.w);
    ((ushort4*)dst)[i] = un.u;
  }
}

// ---------------- 128x128 bf16 MFMA GEMM core (C = A * W^T), K=1024, BK=32 ----------------
__device__ __forceinline__ void gemm_core(const bf16* __restrict__ A, const bf16* __restrict__ W,
                                          int rowStart, int colStart,
                                          bf16* As, bf16* Bs, f32x4 acc[4][4]) {
  const int t = threadIdx.x;
  const int lane = t & 63, w = t >> 6;
  const int lg = lane & 15, lh = lane >> 4;
  const int wm = (w >> 1) * 64, wn = (w & 1) * 64;
#pragma unroll
  for (int i = 0; i < 4; ++i)
#pragma unroll
    for (int j = 0; j < 4; ++j) acc[i][j] = (f32x4){0.f, 0.f, 0.f, 0.f};

  for (int kt = 0; kt < DM / 32; ++kt) {
    int kb = kt * 32;
#pragma unroll
    for (int q = 0; q < 2; ++q) {
      int idx = q * 256 + t;
      int row = idx >> 2;
      int ce = (idx & 3) * 8;
      const bf16* ga = A + (size_t)(rowStart + row) * DM + kb + ce;
      const bf16* gb = W + (size_t)(colStart + row) * DM + kb + ce;
      int ldsbase = (q * 256 + w * 64) * 8;  // elems; wave-uniform
      __builtin_amdgcn_global_load_lds((const __attribute__((address_space(1))) void*)ga,
                                       (__attribute__((address_space(3))) void*)(As + ldsbase),
                                       16, 0, 0);
      __builtin_amdgcn_global_load_lds((const __attribute__((address_space(1))) void*)gb,
                                       (__attribute__((address_space(3))) void*)(Bs + ldsbase),
                                       16, 0, 0);
    }
    __syncthreads();
    bf16x8 af[4], bfr[4];
#pragma unroll
    for (int i = 0; i < 4; ++i)
      af[i] = *(const bf16x8*)(As + (wm + i * 16 + lg) * 32 + 8 * lh);
#pragma unroll
    for (int j = 0; j < 4; ++j)
      bfr[j] = *(const bf16x8*)(Bs + (wn + j * 16 + lg) * 32 + 8 * lh);
#pragma unroll
    for (int i = 0; i < 4; ++i)
#pragma unroll
      for (int j = 0; j < 4; ++j)
        acc[i][j] = __builtin_amdgcn_mfma_f32_16x16x32_bf16(af[i], bfr[j], acc[i][j], 0, 0, 0);
    __syncthreads();
  }
}

// ---------------- QKV projection: z=0 -> Q (pre-scaled), z=1 -> K, z=2 -> V transposed ----------------
__global__ __launch_bounds__(256) void gemm_qkv_kernel(
    const bf16* __restrict__ xb,
    const bf16* __restrict__ Wqb, const bf16* __restrict__ Wkb, const bf16* __restrict__ Wvb,
    const float* __restrict__ bq, const float* __restrict__ bk, const float* __restrict__ bv,
    bf16* __restrict__ Qb, bf16* __restrict__ Kb, bf16* __restrict__ Vt) {
  __shared__ bf16 smem[128 * 128];   // As(8KB) + Bs(8KB) during core; T(32KB) for V transpose
  bf16* As = smem;
  bf16* Bs = smem + 4096;
  const int z = blockIdx.z;
  const bf16* W = (z == 0) ? Wqb : (z == 1) ? Wkb : Wvb;
  const float* bias = (z == 0) ? bq : (z == 1) ? bk : bv;
  int rowStart = blockIdx.y * 128, colStart = blockIdx.x * 128;
  f32x4 acc[4][4];
  gemm_core(xb, W, rowStart, colStart, As, Bs, acc);

  const int t = threadIdx.x, lane = t & 63, w = t >> 6;
  const int lg = lane & 15, lh = lane >> 4;
  const int wm = (w >> 1) * 64, wn = (w & 1) * 64;
  if (z < 2) {
    bf16* out = (z == 0) ? Qb : Kb;
    const float sc = (z == 0) ? QSCALE : 1.0f;
#pragma unroll
    for (int i = 0; i < 4; ++i)
#pragma unroll
      for (int j = 0; j < 4; ++j) {
        int col = colStart + wn + j * 16 + lg;
        float bb = bias[col];
#pragma unroll
        for (int r = 0; r < 4; ++r) {
          int row = rowStart + wm + i * 16 + 4 * lh + r;
          out[(size_t)row * DM + col] = __float2bfloat16((acc[i][j][r] + bb) * sc);
        }
      }
  } else {
    // V: transpose via LDS, then coalesced stores -> Vt[((b*NH+h)*DKK + d)*SL + s]
    char* T = (char*)smem;  // [col 0..127][row 0..127] bf16, swizzled ^((col&7)<<4)
    __syncthreads();
#pragma unroll
    for (int i = 0; i < 4; ++i)
#pragma unroll
      for (int j = 0; j < 4; ++j) {
        int col = wn + j * 16 + lg;
        float bb = bias[colStart + col];
        const int swz = (col & 7) << 4;
#pragma unroll
        for (int r2 = 0; r2 < 4; r2 += 2) {
          int row = wm + i * 16 + 4 * lh + r2;
          union { bf16 hh[2]; unsigned u; } un;
          un.hh[0] = __float2bfloat16(acc[i][j][r2] + bb);
          un.hh[1] = __float2bfloat16(acc[i][j][r2 + 1] + bb);
          *(unsigned*)(T + ((col * 256 + row * 2) ^ swz)) = un.u;
        }
      }
    __syncthreads();
    const int b_i = rowStart >> 11;
    const int sbase = rowStart & 2047;
#pragma unroll
    for (int rd = 0; rd < 8; ++rd) {
      int d_loc = rd * 16 + (t >> 4);
      int s8 = (t & 15) * 8;
      bf16x8 v = *(const bf16x8*)(T + ((d_loc * 256 + s8 * 2) ^ ((d_loc & 7) << 4)));
      int col = colStart + d_loc;
      int h2 = col >> 6, d = col & 63;
      *(bf16x8*)(Vt + ((size_t)(b_i * NH + h2) * DKK + d) * SL + sbase + s8) = v;
    }
  }
}

// ---------------- attention kernel A: softmax denominators only ----------------
__global__ __launch_bounds__(256) void attn_den_kernel(
    const bf16* __restrict__ Qb, const bf16* __restrict__ Kb,
    float* __restrict__ linv_g) {
  __shared__ float sl[2 * 128];
  const int t = threadIdx.x, lane = t & 63, w = t >> 6;
  const int lg = lane & 15, lh = lane >> 4;
  const int L = blockIdx.x;              // 0..511
  const int xcd = L & 7, s_in = L >> 3;
  const int bh = xcd * 4 + (s_in >> 4);
  const int qtile = s_in & 15;
  const int b = bh >> 4, h = bh & 15;
  const int qbase = qtile * 128;
  const int wr = w >> 1, wc = w & 1;

  bf16x8 qf[4][2];
#pragma unroll
  for (int i = 0; i < 4; ++i)
#pragma unroll
    for (int ks = 0; ks < 2; ++ks)
      qf[i][ks] = *(const bf16x8*)(Qb +
          (size_t)(b * SL + qbase + wr * 64 + i * 16 + lg) * DM + h * DKK + ks * 32 + 8 * lh);

  const bf16* Kbase = Kb + (size_t)b * SL * DM + h * DKK;

  float lsum[4] = {0.f, 0.f, 0.f, 0.f};
  for (int kt = 0; kt < 16; ++kt) {
    bf16x8 kf[4][2];
#pragma unroll
    for (int j = 0; j < 4; ++j)
#pragma unroll
      for (int ks = 0; ks < 2; ++ks)
        kf[j][ks] = *(const bf16x8*)(Kbase +
            (size_t)(kt * 128 + wc * 64 + j * 16 + lg) * DM + ks * 32 + 8 * lh);
#pragma unroll
    for (int i = 0; i < 4; ++i) {
      f32x4 s[4];
#pragma unroll
      for (int j = 0; j < 4; ++j) {
        f32x4 z = (f32x4){0.f, 0.f, 0.f, 0.f};
        z = __builtin_amdgcn_mfma_f32_16x16x32_bf16(kf[j][0], qf[i][0], z, 0, 0, 0);
        s[j] = __builtin_amdgcn_mfma_f32_16x16x32_bf16(kf[j][1], qf[i][1], z, 0, 0, 0);
      }
#pragma unroll
      for (int j = 0; j < 4; ++j)
#pragma unroll
        for (int r = 0; r < 4; ++r) lsum[i] += exp2f(s[j][r]);
    }
  }
#pragma unroll
  for (int i = 0; i < 4; ++i) {
    lsum[i] += __shfl_xor(lsum[i], 16);
    lsum[i] += __shfl_xor(lsum[i], 32);
  }
  if (lh == 0) {
#pragma unroll
    for (int i = 0; i < 4; ++i) sl[wc * 128 + wr * 64 + i * 16 + lg] = lsum[i];
  }
  __syncthreads();
  if (t < 128) {
    linv_g[(size_t)bh * SL + qbase + t] = 1.f / (sl[t] + sl[128 + t]);
  }
}

// ---------------- attention kernel B: high-occupancy (16 q-rows/wave, ~110 VGPR) ----------------
// 1024 blocks x 4 waves; wave = 16 q-rows x ALL keys; kf as 2-deep j-pair prefetch ring;
// V loaded inside PV loop; P wave-private [2][16][128] bf16. Target 4+ waves/SIMD.
__global__ __launch_bounds__(256) void attn_wr_kernel(
    const bf16* __restrict__ Qb, const bf16* __restrict__ Kb, const bf16* __restrict__ Vt,
    const float* __restrict__ linv_g,
    float* __restrict__ attn_out, bf16* __restrict__ ctxb) {
  __shared__ bf16 Ps[4][2][16 * 128];  // 32 KB total
  const int t = threadIdx.x, lane = t & 63, w = t >> 6;
  const int lg = lane & 15, lh = lane >> 4;
  const int L = blockIdx.x;              // 0..1023
  const int xcd = L & 7, s_in = L >> 3;  // s_in 0..127
  const int bh = xcd * 4 + (s_in >> 5);
  const int qtile = s_in & 31;
  const int b = bh >> 4, h = bh & 15;
  const int qb2 = qtile * 64 + w * 16;   // this wave's 16 q-rows
  char* Pw = (char*)(&Ps[w][0][0]);

  bf16x8 qf[2];
#pragma unroll
  for (int ks = 0; ks < 2; ++ks)
    qf[ks] = *(const bf16x8*)(Qb +
        (size_t)(b * SL + qb2 + lg) * DM + h * DKK + ks * 32 + 8 * lh);

  const float linv = linv_g[(size_t)bh * SL + qb2 + lg];  // q-row lg

  const bf16* Kbase = Kb + (size_t)b * SL * DM + h * DKK;
  const bf16* Vtb = Vt + (size_t)bh * DKK * SL;
  float* attn_base = attn_out + (size_t)bh * SL * SL;

  f32x4 cacc[4];
#pragma unroll
  for (int jd = 0; jd < 4; ++jd) cacc[jd] = (f32x4){0.f, 0.f, 0.f, 0.f};

  for (int kt = 0; kt < 16; ++kt) {
    char* Pb = Pw + (kt & 1) * 4096;
    // j-pair prefetch ring: kf[buf][jj][ks]
    bf16x8 kf[2][2][2];
#pragma unroll
    for (int jj = 0; jj < 2; ++jj)
#pragma unroll
      for (int ks = 0; ks < 2; ++ks)
        kf[0][jj][ks] = *(const bf16x8*)(Kbase +
            (size_t)(kt * 128 + jj * 16 + lg) * DM + ks * 32 + 8 * lh);
#pragma unroll
    for (int jp = 0; jp < 4; ++jp) {
      const int cur = jp & 1, nxt = cur ^ 1;
      if (jp < 3) {
#pragma unroll
        for (int jj = 0; jj < 2; ++jj)
#pragma unroll
          for (int ks = 0; ks < 2; ++ks)
            kf[nxt][jj][ks] = *(const bf16x8*)(Kbase +
                (size_t)(kt * 128 + (jp + 1) * 32 + jj * 16 + lg) * DM + ks * 32 + 8 * lh);
      }
#pragma unroll
      for (int jj = 0; jj < 2; ++jj) {
        const int j = jp * 2 + jj;
        f32x4 z = (f32x4){0.f, 0.f, 0.f, 0.f};
        z = __builtin_amdgcn_mfma_f32_16x16x32_bf16(kf[cur][jj][0], qf[0], z, 0, 0, 0);
        f32x4 s = __builtin_amdgcn_mfma_f32_16x16x32_bf16(kf[cur][jj][1], qf[1], z, 0, 0, 0);
        // lane: q-row = lg, key = kt*128 + j*16 + 4*lh + r
        f32x4 p4;
        p4[0] = exp2f(s[0]) * linv;
        p4[1] = exp2f(s[1]) * linv;
        p4[2] = exp2f(s[2]) * linv;
        p4[3] = exp2f(s[3]) * linv;
        __builtin_nontemporal_store(p4,
            (f32x4*)(attn_base + (size_t)(qb2 + lg) * SL + kt * 128 + j * 16 + 4 * lh));
        union { bf16 hh[4]; ushort4 u4; } un;
        un.hh[0] = __float2bfloat16(p4[0]);
        un.hh[1] = __float2bfloat16(p4[1]);
        un.hh[2] = __float2bfloat16(p4[2]);
        un.hh[3] = __float2bfloat16(p4[3]);
        *(ushort4*)(Pb + ((lg * 256 + (j * 16 + 4 * lh) * 2) ^ ((lg & 7) << 4))) = un.u4;
      }
    }

    // PV for this kt: P from wave-private LDS, V streamed
#pragma unroll
    for (int ks = 0; ks < 4; ++ks) {
      bf16x8 pf = *(const bf16x8*)(Pb +
          ((lg * 256 + (ks * 32 + 8 * lh) * 2) ^ ((lg & 7) << 4)));
      bf16x8 vf[4];
#pragma unroll
      for (int jd = 0; jd < 4; ++jd)
        vf[jd] = *(const bf16x8*)(Vtb +
            (size_t)(jd * 16 + lg) * SL + kt * 128 + ks * 32 + 8 * lh);
      __builtin_amdgcn_s_setprio(1);
#pragma unroll
      for (int jd = 0; jd < 4; ++jd)
        cacc[jd] = __builtin_amdgcn_mfma_f32_16x16x32_bf16(pf, vf[jd], cacc[jd], 0, 0, 0);
      __builtin_amdgcn_s_setprio(0);
    }
  }

  // ctx (already normalized): wave's rows 4*lh+r, cols jd*16+lg
#pragma unroll
  for (int jd = 0; jd < 4; ++jd)
#pragma unroll
    for (int r = 0; r < 4; ++r) {
      int row = qb2 + 4 * lh + r;
      int d = jd * 16 + lg;
      ctxb[(size_t)(b * SL + row) * DM + h * DKK + d] = __float2bfloat16(cacc[jd][r]);
    }
}

// ---------------- O projection + bias + residual (128x64 tiles) ----------------
__global__ __launch_bounds__(256) void gemm_o_kernel(
    const bf16* __restrict__ ctxb, const bf16* __restrict__ Wob, const float* __restrict__ bo,
    const float* __restrict__ xf, float* __restrict__ ypre) {
  __shared__ bf16 As[128 * 32], Bs[64 * 32];
  const int t = threadIdx.x, lane = t & 63, w = t >> 6;
  const int lg = lane & 15, lh = lane >> 4;
  const int wm = (w >> 1) * 64, wn = (w & 1) * 32;
  int rowStart = blockIdx.y * 128, colStart = blockIdx.x * 64;
  f32x4 acc[4][2];
#pragma unroll
  for (int i = 0; i < 4; ++i)
#pragma unroll
    for (int j = 0; j < 2; ++j) acc[i][j] = (f32x4){0.f, 0.f, 0.f, 0.f};

  for (int kt = 0; kt < DM / 32; ++kt) {
    int kb = kt * 32;
#pragma unroll
    for (int q = 0; q < 2; ++q) {
      int idx = q * 256 + t;
      int row = idx >> 2;
      int ce = (idx & 3) * 8;
      const bf16* ga = ctxb + (size_t)(rowStart + row) * DM + kb + ce;
      int ldsbase = (q * 256 + w * 64) * 8;
      __builtin_amdgcn_global_load_lds((const __attribute__((address_space(1))) void*)ga,
                                       (__attribute__((address_space(3))) void*)(As + ldsbase),
                                       16, 0, 0);
    }
    {
      int row = t >> 2, ce = (t & 3) * 8;
      const bf16* gb = Wob + (size_t)(colStart + row) * DM + kb + ce;
      int ldsbase = (w * 64) * 8;
      __builtin_amdgcn_global_load_lds((const __attribute__((address_space(1))) void*)gb,
                                       (__attribute__((address_space(3))) void*)(Bs + ldsbase),
                                       16, 0, 0);
    }
    __syncthreads();
    bf16x8 af[4], bfr[2];
#pragma unroll
    for (int i = 0; i < 4; ++i)
      af[i] = *(const bf16x8*)(As + (wm + i * 16 + lg) * 32 + 8 * lh);
#pragma unroll
    for (int j = 0; j < 2; ++j)
      bfr[j] = *(const bf16x8*)(Bs + (wn + j * 16 + lg) * 32 + 8 * lh);
#pragma unroll
    for (int i = 0; i < 4; ++i)
#pragma unroll
      for (int j = 0; j < 2; ++j)
        acc[i][j] = __builtin_amdgcn_mfma_f32_16x16x32_bf16(af[i], bfr[j], acc[i][j], 0, 0, 0);
    __syncthreads();
  }
#pragma unroll
  for (int i = 0; i < 4; ++i)
#pragma unroll
    for (int j = 0; j < 2; ++j) {
      int col = colStart + wn + j * 16 + lg;
      float bb = bo[col];
#pragma unroll
      for (int r = 0; r < 4; ++r) {
        int row = rowStart + wm + i * 16 + 4 * lh + r;
        ypre[(size_t)row * DM + col] = acc[i][j][r] + bb + xf[(size_t)row * DM + col];
      }
    }
}

// ---------------- row LayerNorm ----------------
__global__ __launch_bounds__(256) void ln_kernel(const float* __restrict__ ypre,
                                                 const float* __restrict__ g,
                                                 const float* __restrict__ bta,
                                                 float* __restrict__ out) {
  int row = blockIdx.x;
  const float* yr = ypre + (size_t)row * DM;
  int t = threadIdx.x;
  float4 v = *(const float4*)(yr + t * 4);
  float s = v.x + v.y + v.z + v.w;
  float ss = v.x * v.x + v.y * v.y + v.z * v.z + v.w * v.w;
#pragma unroll
  for (int off = 1; off < 64; off <<= 1) {
    s += __shfl_xor(s, off);
    ss += __shfl_xor(ss, off);
  }
  __shared__ float red[8];
  int w = t >> 6, lane = t & 63;
  if (lane == 0) { red[w] = s; red[4 + w] = ss; }
  __syncthreads();
  s = red[0] + red[1] + red[2] + red[3];
  ss = red[4] + red[5] + red[6] + red[7];
  float mu = s * (1.f / (float)DM);
  float var = ss * (1.f / (float)DM) - mu * mu;
  float rstd = rsqrtf(var + 1e-5f);
  float4 gv = *(const float4*)(g + t * 4);
  float4 bv = *(const float4*)(bta + t * 4);
  float4 o;
  o.x = (v.x - mu) * rstd * gv.x + bv.x;
  o.y = (v.y - mu) * rstd * gv.y + bv.y;
  o.z = (v.z - mu) * rstd * gv.z + bv.z;
  o.w = (v.w - mu) * rstd * gv.w + bv.w;
  *(float4*)(out + (size_t)row * DM + t * 4) = o;
}

extern "C" void kernel_launch(void* const* d_in, const int* in_sizes, int n_in,
                              void* d_out, int out_size, void* d_ws, size_t ws_size,
                              hipStream_t stream) {
  (void)in_sizes; (void)n_in; (void)out_size; (void)ws_size;
  const float* x = (const float*)d_in[0];
  // d_in[1] (reasoning_state), d_in[8] (Wr), d_in[9] (br): softmax-shift-invariant, unused
  const float* Wq = (const float*)d_in[2];
  const float* bq = (const float*)d_in[3];
  const float* Wk = (const float*)d_in[4];
  const float* bk = (const float*)d_in[5];
  const float* Wv = (const float*)d_in[6];
  const float* bv = (const float*)d_in[7];
  const float* Wo = (const float*)d_in[10];
  const float* bo = (const float*)d_in[11];
  const float* ln_g = (const float*)d_in[12];
  const float* ln_b = (const float*)d_in[13];
  float* out = (float*)d_out;

  char* ws = (char*)d_ws;
  const size_t MB = 1ull << 20;
  bf16* xb   = (bf16*)(ws + 0 * MB);    // 8 MB
  bf16* Wqb  = (bf16*)(ws + 8 * MB);    // 2 MB
  bf16* Wkb  = (bf16*)(ws + 10 * MB);   // 2 MB
  bf16* Wvb  = (bf16*)(ws + 12 * MB);   // 2 MB
  bf16* Wob  = (bf16*)(ws + 14 * MB);   // 2 MB
  bf16* Qb   = (bf16*)(ws + 16 * MB);   // 8 MB (pre-scaled by QSCALE)
  bf16* Kb   = (bf16*)(ws + 24 * MB);   // 8 MB
  bf16* Vt   = (bf16*)(ws + 32 * MB);   // 8 MB, [B,H,dk,S]
  bf16* ctxb = (bf16*)(ws + 40 * MB);   // 8 MB
  float* ypre = (float*)(ws + 48 * MB); // 16 MB
  float* linv_g = (float*)(ws + 64 * MB); // 256 KB

  float* y_out = out;                       // 4 M floats
  float* attn_out = out + (size_t)NR * DM;  // 134 M floats

  cvt5_kernel<<<dim3(512, 5), 256, 0, stream>>>(x, Wq, Wk, Wv, Wo, xb, Wqb, Wkb, Wvb, Wob);

  gemm_qkv_kernel<<<dim3(8, 32, 3), 256, 0, stream>>>(xb, Wqb, Wkb, Wvb, bq, bk, bv, Qb, Kb, Vt);
  attn_den_kernel<<<512, 256, 0, stream>>>(Qb, Kb, linv_g);
  attn_wr_kernel<<<1024, 256, 0, stream>>>(Qb, Kb, Vt, linv_g, attn_out, ctxb);
  gemm_o_kernel<<<dim3(16, 32), 256, 0, stream>>>(ctxb, Wob, bo, x, ypre);
  ln_kernel<<<4096, 256, 0, stream>>>(ypre, ln_g, ln_b, y_out);
}

// Round 13
// 339.050 us; speedup vs baseline: 1.0957x; 1.0957x over previous
//
#include <hip/hip_runtime.h>
#include <hip/hip_bf16.h>

#define DM 1024
#define NH 16
#define DKK 64
#define SL 2048
#define NBATCH 2
#define NR (NBATCH*SL)   // 4096 rows

typedef __attribute__((ext_vector_type(8))) __bf16 bf16x8;
typedef __attribute__((ext_vector_type(4))) float f32x4;
using bf16 = __hip_bfloat16;

// Q pre-scale: 1/sqrt(64) * log2(e), so exp2(s) == exp(s_orig/8)
#define QSCALE 0.18033688011112042f

// ---------------- merged fp32 -> bf16 converts: y=0 -> x, y=1..4 -> weights ----------------
__global__ __launch_bounds__(256) void cvt5_kernel(
    const float* __restrict__ sx, const float* __restrict__ s1,
    const float* __restrict__ s2, const float* __restrict__ s3, const float* __restrict__ s4,
    bf16* __restrict__ dx, bf16* __restrict__ d1,
    bf16* __restrict__ d2, bf16* __restrict__ d3, bf16* __restrict__ d4) {
  const int z = blockIdx.y;
  const float* src = (z == 0) ? sx : (z == 1) ? s1 : (z == 2) ? s2 : (z == 3) ? s3 : s4;
  bf16* dst = (z == 0) ? dx : (z == 1) ? d1 : (z == 2) ? d2 : (z == 3) ? d3 : d4;
  const int n4 = (z == 0) ? (NR * DM / 4) : (DM * DM / 4);
  int stride = gridDim.x * blockDim.x;
  for (int i = blockIdx.x * blockDim.x + threadIdx.x; i < n4; i += stride) {
    float4 v = ((const float4*)src)[i];
    union { bf16 h[4]; ushort4 u; } un;
    un.h[0] = __float2bfloat16(v.x);
    un.h[1] = __float2bfloat16(v.y);
    un.h[2] = __float2bfloat16(v.z);
    un.h[3] = __float2bfloat16(v.w);
    ((ushort4*)dst)[i] = un.u;
  }
}

// ---------------- 128x128 bf16 MFMA GEMM core (C = A * W^T), K=1024, BK=32 ----------------
__device__ __forceinline__ void gemm_core(const bf16* __restrict__ A, const bf16* __restrict__ W,
                                          int rowStart, int colStart,
                                          bf16* As, bf16* Bs, f32x4 acc[4][4]) {
  const int t = threadIdx.x;
  const int lane = t & 63, w = t >> 6;
  const int lg = lane & 15, lh = lane >> 4;
  const int wm = (w >> 1) * 64, wn = (w & 1) * 64;
#pragma unroll
  for (int i = 0; i < 4; ++i)
#pragma unroll
    for (int j = 0; j < 4; ++j) acc[i][j] = (f32x4){0.f, 0.f, 0.f, 0.f};

  for (int kt = 0; kt < DM / 32; ++kt) {
    int kb = kt * 32;
#pragma unroll
    for (int q = 0; q < 2; ++q) {
      int idx = q * 256 + t;
      int row = idx >> 2;
      int ce = (idx & 3) * 8;
      const bf16* ga = A + (size_t)(rowStart + row) * DM + kb + ce;
      const bf16* gb = W + (size_t)(colStart + row) * DM + kb + ce;
      int ldsbase = (q * 256 + w * 64) * 8;  // elems; wave-uniform
      __builtin_amdgcn_global_load_lds((const __attribute__((address_space(1))) void*)ga,
                                       (__attribute__((address_space(3))) void*)(As + ldsbase),
                                       16, 0, 0);
      __builtin_amdgcn_global_load_lds((const __attribute__((address_space(1))) void*)gb,
                                       (__attribute__((address_space(3))) void*)(Bs + ldsbase),
                                       16, 0, 0);
    }
    __syncthreads();
    bf16x8 af[4], bfr[4];
#pragma unroll
    for (int i = 0; i < 4; ++i)
      af[i] = *(const bf16x8*)(As + (wm + i * 16 + lg) * 32 + 8 * lh);
#pragma unroll
    for (int j = 0; j < 4; ++j)
      bfr[j] = *(const bf16x8*)(Bs + (wn + j * 16 + lg) * 32 + 8 * lh);
#pragma unroll
    for (int i = 0; i < 4; ++i)
#pragma unroll
      for (int j = 0; j < 4; ++j)
        acc[i][j] = __builtin_amdgcn_mfma_f32_16x16x32_bf16(af[i], bfr[j], acc[i][j], 0, 0, 0);
    __syncthreads();
  }
}

// ---------------- QKV projection: z=0 -> Q (pre-scaled), z=1 -> K, z=2 -> V transposed ----------------
__global__ __launch_bounds__(256) void gemm_qkv_kernel(
    const bf16* __restrict__ xb,
    const bf16* __restrict__ Wqb, const bf16* __restrict__ Wkb, const bf16* __restrict__ Wvb,
    const float* __restrict__ bq, const float* __restrict__ bk, const float* __restrict__ bv,
    bf16* __restrict__ Qb, bf16* __restrict__ Kb, bf16* __restrict__ Vt) {
  __shared__ bf16 smem[128 * 128];   // As(8KB) + Bs(8KB) during core; T(32KB) for V transpose
  bf16* As = smem;
  bf16* Bs = smem + 4096;
  const int z = blockIdx.z;
  const bf16* W = (z == 0) ? Wqb : (z == 1) ? Wkb : Wvb;
  const float* bias = (z == 0) ? bq : (z == 1) ? bk : bv;
  int rowStart = blockIdx.y * 128, colStart = blockIdx.x * 128;
  f32x4 acc[4][4];
  gemm_core(xb, W, rowStart, colStart, As, Bs, acc);

  const int t = threadIdx.x, lane = t & 63, w = t >> 6;
  const int lg = lane & 15, lh = lane >> 4;
  const int wm = (w >> 1) * 64, wn = (w & 1) * 64;
  if (z < 2) {
    bf16* out = (z == 0) ? Qb : Kb;
    const float sc = (z == 0) ? QSCALE : 1.0f;
#pragma unroll
    for (int i = 0; i < 4; ++i)
#pragma unroll
      for (int j = 0; j < 4; ++j) {
        int col = colStart + wn + j * 16 + lg;
        float bb = bias[col];
#pragma unroll
        for (int r = 0; r < 4; ++r) {
          int row = rowStart + wm + i * 16 + 4 * lh + r;
          out[(size_t)row * DM + col] = __float2bfloat16((acc[i][j][r] + bb) * sc);
        }
      }
  } else {
    // V: transpose via LDS, then coalesced stores -> Vt[((b*NH+h)*DKK + d)*SL + s]
    char* T = (char*)smem;  // [col 0..127][row 0..127] bf16, swizzled ^((col&7)<<4)
    __syncthreads();
#pragma unroll
    for (int i = 0; i < 4; ++i)
#pragma unroll
      for (int j = 0; j < 4; ++j) {
        int col = wn + j * 16 + lg;
        float bb = bias[colStart + col];
        const int swz = (col & 7) << 4;
#pragma unroll
        for (int r2 = 0; r2 < 4; r2 += 2) {
          int row = wm + i * 16 + 4 * lh + r2;
          union { bf16 hh[2]; unsigned u; } un;
          un.hh[0] = __float2bfloat16(acc[i][j][r2] + bb);
          un.hh[1] = __float2bfloat16(acc[i][j][r2 + 1] + bb);
          *(unsigned*)(T + ((col * 256 + row * 2) ^ swz)) = un.u;
        }
      }
    __syncthreads();
    const int b_i = rowStart >> 11;
    const int sbase = rowStart & 2047;
#pragma unroll
    for (int rd = 0; rd < 8; ++rd) {
      int d_loc = rd * 16 + (t >> 4);
      int s8 = (t & 15) * 8;
      bf16x8 v = *(const bf16x8*)(T + ((d_loc * 256 + s8 * 2) ^ ((d_loc & 7) << 4)));
      int col = colStart + d_loc;
      int h2 = col >> 6, d = col & 63;
      *(bf16x8*)(Vt + ((size_t)(b_i * NH + h2) * DKK + d) * SL + sbase + s8) = v;
    }
  }
}

// ---------------- attention kernel A: softmax denominators only ----------------
__global__ __launch_bounds__(256) void attn_den_kernel(
    const bf16* __restrict__ Qb, const bf16* __restrict__ Kb,
    float* __restrict__ linv_g) {
  __shared__ float sl[2 * 128];
  const int t = threadIdx.x, lane = t & 63, w = t >> 6;
  const int lg = lane & 15, lh = lane >> 4;
  const int L = blockIdx.x;              // 0..511
  const int xcd = L & 7, s_in = L >> 3;
  const int bh = xcd * 4 + (s_in >> 4);
  const int qtile = s_in & 15;
  const int b = bh >> 4, h = bh & 15;
  const int qbase = qtile * 128;
  const int wr = w >> 1, wc = w & 1;

  bf16x8 qf[4][2];
#pragma unroll
  for (int i = 0; i < 4; ++i)
#pragma unroll
    for (int ks = 0; ks < 2; ++ks)
      qf[i][ks] = *(const bf16x8*)(Qb +
          (size_t)(b * SL + qbase + wr * 64 + i * 16 + lg) * DM + h * DKK + ks * 32 + 8 * lh);

  const bf16* Kbase = Kb + (size_t)b * SL * DM + h * DKK;

  float lsum[4] = {0.f, 0.f, 0.f, 0.f};
  for (int kt = 0; kt < 16; ++kt) {
    bf16x8 kf[4][2];
#pragma unroll
    for (int j = 0; j < 4; ++j)
#pragma unroll
      for (int ks = 0; ks < 2; ++ks)
        kf[j][ks] = *(const bf16x8*)(Kbase +
            (size_t)(kt * 128 + wc * 64 + j * 16 + lg) * DM + ks * 32 + 8 * lh);
#pragma unroll
    for (int i = 0; i < 4; ++i) {
      f32x4 s[4];
#pragma unroll
      for (int j = 0; j < 4; ++j) {
        f32x4 z = (f32x4){0.f, 0.f, 0.f, 0.f};
        z = __builtin_amdgcn_mfma_f32_16x16x32_bf16(kf[j][0], qf[i][0], z, 0, 0, 0);
        s[j] = __builtin_amdgcn_mfma_f32_16x16x32_bf16(kf[j][1], qf[i][1], z, 0, 0, 0);
      }
#pragma unroll
      for (int j = 0; j < 4; ++j)
#pragma unroll
        for (int r = 0; r < 4; ++r) lsum[i] += exp2f(s[j][r]);
    }
  }
#pragma unroll
  for (int i = 0; i < 4; ++i) {
    lsum[i] += __shfl_xor(lsum[i], 16);
    lsum[i] += __shfl_xor(lsum[i], 32);
  }
  if (lh == 0) {
#pragma unroll
    for (int i = 0; i < 4; ++i) sl[wc * 128 + wr * 64 + i * 16 + lg] = lsum[i];
  }
  __syncthreads();
  if (t < 128) {
    linv_g[(size_t)bh * SL + qbase + t] = 1.f / (sl[t] + sl[128 + t]);
  }
}

// ---------------- attention kernel B: r11 structure, PLAIN stores (NT removed) ----------------
// Single-variable A/B vs round 11: __builtin_nontemporal_store -> plain store.
// Theory: NT (NOALLOC) bypasses L2 write-combining; our 64B/row scatter then relies on the
// MC write combiner, which overflows under 2048 concurrent waves -> partial-line HBM bursts.
// Plain stores coalesce in L2 like the 6.8 TB/s harness fills do.
__global__ __launch_bounds__(256) void attn_wr_kernel(
    const bf16* __restrict__ Qb, const bf16* __restrict__ Kb, const bf16* __restrict__ Vt,
    const float* __restrict__ linv_g,
    float* __restrict__ attn_out, bf16* __restrict__ ctxb) {
  __shared__ bf16 Ps[4][2][32 * 128];  // [wave][buf][q][key] = 64 KB total
  const int t = threadIdx.x, lane = t & 63, w = t >> 6;
  const int lg = lane & 15, lh = lane >> 4;
  const int L = blockIdx.x;              // 0..511
  const int xcd = L & 7, s_in = L >> 3;
  const int bh = xcd * 4 + (s_in >> 4);
  const int qtile = s_in & 15;
  const int b = bh >> 4, h = bh & 15;
  const int qb2 = qtile * 128 + w * 32;  // this wave's 32 q-rows
  char* Pw = (char*)(&Ps[w][0][0]);

  bf16x8 qf[2][2];
#pragma unroll
  for (int i = 0; i < 2; ++i)
#pragma unroll
    for (int ks = 0; ks < 2; ++ks)
      qf[i][ks] = *(const bf16x8*)(Qb +
          (size_t)(b * SL + qb2 + i * 16 + lg) * DM + h * DKK + ks * 32 + 8 * lh);

  float linv[2];
#pragma unroll
  for (int i = 0; i < 2; ++i)
    linv[i] = linv_g[(size_t)bh * SL + qb2 + i * 16 + lg];

  const bf16* Kbase = Kb + (size_t)b * SL * DM + h * DKK;
  const bf16* Vtb = Vt + (size_t)bh * DKK * SL;
  float* attn_base = attn_out + (size_t)bh * SL * SL;

  f32x4 cacc[2][4];
#pragma unroll
  for (int i = 0; i < 2; ++i)
#pragma unroll
    for (int jd = 0; jd < 4; ++jd) cacc[i][jd] = (f32x4){0.f, 0.f, 0.f, 0.f};

  for (int kt = 0; kt < 16; ++kt) {
    char* Pb = Pw + (kt & 1) * 8192;
    // --- all global loads for this kt issued FIRST (older than this kt's stores) ---
    bf16x8 kf[8][2];
#pragma unroll
    for (int j = 0; j < 8; ++j)
#pragma unroll
      for (int ks = 0; ks < 2; ++ks)
        kf[j][ks] = *(const bf16x8*)(Kbase +
            (size_t)(kt * 128 + j * 16 + lg) * DM + ks * 32 + 8 * lh);
    bf16x8 vfall[4][4];
#pragma unroll
    for (int ks = 0; ks < 4; ++ks)
#pragma unroll
      for (int jd = 0; jd < 4; ++jd)
        vfall[ks][jd] = *(const bf16x8*)(Vtb +
            (size_t)(jd * 16 + lg) * SL + kt * 128 + ks * 32 + 8 * lh);

    // --- QK^T + exp2 -> normalized P: PLAIN scatter store + LDS write ---
#pragma unroll
    for (int i = 0; i < 2; ++i) {
      f32x4 s[8];
      __builtin_amdgcn_s_setprio(1);
#pragma unroll
      for (int j = 0; j < 8; ++j) {
        f32x4 z = (f32x4){0.f, 0.f, 0.f, 0.f};
        z = __builtin_amdgcn_mfma_f32_16x16x32_bf16(kf[j][0], qf[i][0], z, 0, 0, 0);
        s[j] = __builtin_amdgcn_mfma_f32_16x16x32_bf16(kf[j][1], qf[i][1], z, 0, 0, 0);
      }
      __builtin_amdgcn_s_setprio(0);
      const int qloc = i * 16 + lg;
      const int swz = (qloc & 7) << 4;
#pragma unroll
      for (int j = 0; j < 8; ++j) {
        const int key0 = j * 16 + 4 * lh;
        f32x4 p4;
        p4[0] = exp2f(s[j][0]) * linv[i];
        p4[1] = exp2f(s[j][1]) * linv[i];
        p4[2] = exp2f(s[j][2]) * linv[i];
        p4[3] = exp2f(s[j][3]) * linv[i];
        *(f32x4*)(attn_base + (size_t)(qb2 + qloc) * SL + kt * 128 + key0) = p4;
        union { bf16 hh[4]; ushort4 u4; } un;
        un.hh[0] = __float2bfloat16(p4[0]);
        un.hh[1] = __float2bfloat16(p4[1]);
        un.hh[2] = __float2bfloat16(p4[2]);
        un.hh[3] = __float2bfloat16(p4[3]);
        *(ushort4*)(Pb + ((qloc * 256 + key0 * 2) ^ swz)) = un.u4;
      }
    }

    // --- PV: P from LDS, V already in regs (wait on V leaves stores in flight) ---
    __builtin_amdgcn_s_setprio(1);
#pragma unroll
    for (int ks = 0; ks < 4; ++ks) {
      bf16x8 pf[2];
#pragma unroll
      for (int i = 0; i < 2; ++i) {
        const int qloc = i * 16 + lg;
        pf[i] = *(const bf16x8*)(Pb + ((qloc * 256 + (ks * 32 + 8 * lh) * 2) ^ ((qloc & 7) << 4)));
      }
#pragma unroll
      for (int i = 0; i < 2; ++i)
#pragma unroll
        for (int jd = 0; jd < 4; ++jd)
          cacc[i][jd] = __builtin_amdgcn_mfma_f32_16x16x32_bf16(pf[i], vfall[ks][jd], cacc[i][jd], 0, 0, 0);
    }
    __builtin_amdgcn_s_setprio(0);
  }

  // ctx (already normalized) -> [B*S, DM] bf16
#pragma unroll
  for (int i = 0; i < 2; ++i)
#pragma unroll
    for (int jd = 0; jd < 4; ++jd)
#pragma unroll
      for (int r = 0; r < 4; ++r) {
        int row = qb2 + i * 16 + 4 * lh + r;
        int d = jd * 16 + lg;
        ctxb[(size_t)(b * SL + row) * DM + h * DKK + d] = __float2bfloat16(cacc[i][jd][r]);
      }
}

// ---------------- O projection + bias + residual (128x64 tiles) ----------------
__global__ __launch_bounds__(256) void gemm_o_kernel(
    const bf16* __restrict__ ctxb, const bf16* __restrict__ Wob, const float* __restrict__ bo,
    const float* __restrict__ xf, float* __restrict__ ypre) {
  __shared__ bf16 As[128 * 32], Bs[64 * 32];
  const int t = threadIdx.x, lane = t & 63, w = t >> 6;
  const int lg = lane & 15, lh = lane >> 4;
  const int wm = (w >> 1) * 64, wn = (w & 1) * 32;
  int rowStart = blockIdx.y * 128, colStart = blockIdx.x * 64;
  f32x4 acc[4][2];
#pragma unroll
  for (int i = 0; i < 4; ++i)
#pragma unroll
    for (int j = 0; j < 2; ++j) acc[i][j] = (f32x4){0.f, 0.f, 0.f, 0.f};

  for (int kt = 0; kt < DM / 32; ++kt) {
    int kb = kt * 32;
#pragma unroll
    for (int q = 0; q < 2; ++q) {
      int idx = q * 256 + t;
      int row = idx >> 2;
      int ce = (idx & 3) * 8;
      const bf16* ga = ctxb + (size_t)(rowStart + row) * DM + kb + ce;
      int ldsbase = (q * 256 + w * 64) * 8;
      __builtin_amdgcn_global_load_lds((const __attribute__((address_space(1))) void*)ga,
                                       (__attribute__((address_space(3))) void*)(As + ldsbase),
                                       16, 0, 0);
    }
    {
      int row = t >> 2, ce = (t & 3) * 8;
      const bf16* gb = Wob + (size_t)(colStart + row) * DM + kb + ce;
      int ldsbase = (w * 64) * 8;
      __builtin_amdgcn_global_load_lds((const __attribute__((address_space(1))) void*)gb,
                                       (__attribute__((address_space(3))) void*)(Bs + ldsbase),
                                       16, 0, 0);
    }
    __syncthreads();
    bf16x8 af[4], bfr[2];
#pragma unroll
    for (int i = 0; i < 4; ++i)
      af[i] = *(const bf16x8*)(As + (wm + i * 16 + lg) * 32 + 8 * lh);
#pragma unroll
    for (int j = 0; j < 2; ++j)
      bfr[j] = *(const bf16x8*)(Bs + (wn + j * 16 + lg) * 32 + 8 * lh);
#pragma unroll
    for (int i = 0; i < 4; ++i)
#pragma unroll
      for (int j = 0; j < 2; ++j)
        acc[i][j] = __builtin_amdgcn_mfma_f32_16x16x32_bf16(af[i], bfr[j], acc[i][j], 0, 0, 0);
    __syncthreads();
  }
#pragma unroll
  for (int i = 0; i < 4; ++i)
#pragma unroll
    for (int j = 0; j < 2; ++j) {
      int col = colStart + wn + j * 16 + lg;
      float bb = bo[col];
#pragma unroll
      for (int r = 0; r < 4; ++r) {
        int row = rowStart + wm + i * 16 + 4 * lh + r;
        ypre[(size_t)row * DM + col] = acc[i][j][r] + bb + xf[(size_t)row * DM + col];
      }
    }
}

// ---------------- row LayerNorm ----------------
__global__ __launch_bounds__(256) void ln_kernel(const float* __restrict__ ypre,
                                                 const float* __restrict__ g,
                                                 const float* __restrict__ bta,
                                                 float* __restrict__ out) {
  int row = blockIdx.x;
  const float* yr = ypre + (size_t)row * DM;
  int t = threadIdx.x;
  float4 v = *(const float4*)(yr + t * 4);
  float s = v.x + v.y + v.z + v.w;
  float ss = v.x * v.x + v.y * v.y + v.z * v.z + v.w * v.w;
#pragma unroll
  for (int off = 1; off < 64; off <<= 1) {
    s += __shfl_xor(s, off);
    ss += __shfl_xor(ss, off);
  }
  __shared__ float red[8];
  int w = t >> 6, lane = t & 63;
  if (lane == 0) { red[w] = s; red[4 + w] = ss; }
  __syncthreads();
  s = red[0] + red[1] + red[2] + red[3];
  ss = red[4] + red[5] + red[6] + red[7];
  float mu = s * (1.f / (float)DM);
  float var = ss * (1.f / (float)DM) - mu * mu;
  float rstd = rsqrtf(var + 1e-5f);
  float4 gv = *(const float4*)(g + t * 4);
  float4 bv = *(const float4*)(bta + t * 4);
  float4 o;
  o.x = (v.x - mu) * rstd * gv.x + bv.x;
  o.y = (v.y - mu) * rstd * gv.y + bv.y;
  o.z = (v.z - mu) * rstd * gv.z + bv.z;
  o.w = (v.w - mu) * rstd * gv.w + bv.w;
  *(float4*)(out + (size_t)row * DM + t * 4) = o;
}

extern "C" void kernel_launch(void* const* d_in, const int* in_sizes, int n_in,
                              void* d_out, int out_size, void* d_ws, size_t ws_size,
                              hipStream_t stream) {
  (void)in_sizes; (void)n_in; (void)out_size; (void)ws_size;
  const float* x = (const float*)d_in[0];
  // d_in[1] (reasoning_state), d_in[8] (Wr), d_in[9] (br): softmax-shift-invariant, unused
  const float* Wq = (const float*)d_in[2];
  const float* bq = (const float*)d_in[3];
  const float* Wk = (const float*)d_in[4];
  const float* bk = (const float*)d_in[5];
  const float* Wv = (const float*)d_in[6];
  const float* bv = (const float*)d_in[7];
  const float* Wo = (const float*)d_in[10];
  const float* bo = (const float*)d_in[11];
  const float* ln_g = (const float*)d_in[12];
  const float* ln_b = (const float*)d_in[13];
  float* out = (float*)d_out;

  char* ws = (char*)d_ws;
  const size_t MB = 1ull << 20;
  bf16* xb   = (bf16*)(ws + 0 * MB);    // 8 MB
  bf16* Wqb  = (bf16*)(ws + 8 * MB);    // 2 MB
  bf16* Wkb  = (bf16*)(ws + 10 * MB);   // 2 MB
  bf16* Wvb  = (bf16*)(ws + 12 * MB);   // 2 MB
  bf16* Wob  = (bf16*)(ws + 14 * MB);   // 2 MB
  bf16* Qb   = (bf16*)(ws + 16 * MB);   // 8 MB (pre-scaled by QSCALE)
  bf16* Kb   = (bf16*)(ws + 24 * MB);   // 8 MB
  bf16* Vt   = (bf16*)(ws + 32 * MB);   // 8 MB, [B,H,dk,S]
  bf16* ctxb = (bf16*)(ws + 40 * MB);   // 8 MB
  float* ypre = (float*)(ws + 48 * MB); // 16 MB
  float* linv_g = (float*)(ws + 64 * MB); // 256 KB

  float* y_out = out;                       // 4 M floats
  float* attn_out = out + (size_t)NR * DM;  // 134 M floats

  cvt5_kernel<<<dim3(512, 5), 256, 0, stream>>>(x, Wq, Wk, Wv, Wo, xb, Wqb, Wkb, Wvb, Wob);

  gemm_qkv_kernel<<<dim3(8, 32, 3), 256, 0, stream>>>(xb, Wqb, Wkb, Wvb, bq, bk, bv, Qb, Kb, Vt);
  attn_den_kernel<<<512, 256, 0, stream>>>(Qb, Kb, linv_g);
  attn_wr_kernel<<<512, 256, 0, stream>>>(Qb, Kb, Vt, linv_g, attn_out, ctxb);
  gemm_o_kernel<<<dim3(16, 32), 256, 0, stream>>>(ctxb, Wob, bo, x, ypre);
  ln_kernel<<<4096, 256, 0, stream>>>(ypre, ln_g, ln_b, y_out);
}

// Round 14
// 303.090 us; speedup vs baseline: 1.2257x; 1.1186x over previous
//
#include <hip/hip_runtime.h>
#include <hip/hip_bf16.h>

#define DM 1024
#define NH 16
#define DKK 64
#define SL 2048
#define NBATCH 2
#define NR (NBATCH*SL)   // 4096 rows

typedef __attribute__((ext_vector_type(8))) __bf16 bf16x8;
typedef __attribute__((ext_vector_type(4))) float f32x4;
using bf16 = __hip_bfloat16;

// Q pre-scale: 1/sqrt(64) * log2(e), so exp2(s) == exp(s_orig/8)
#define QSCALE 0.18033688011112042f

// ---------------- merged fp32 -> bf16 converts: y=0 -> x, y=1..4 -> weights ----------------
__global__ __launch_bounds__(256) void cvt5_kernel(
    const float* __restrict__ sx, const float* __restrict__ s1,
    const float* __restrict__ s2, const float* __restrict__ s3, const float* __restrict__ s4,
    bf16* __restrict__ dx, bf16* __restrict__ d1,
    bf16* __restrict__ d2, bf16* __restrict__ d3, bf16* __restrict__ d4) {
  const int z = blockIdx.y;
  const float* src = (z == 0) ? sx : (z == 1) ? s1 : (z == 2) ? s2 : (z == 3) ? s3 : s4;
  bf16* dst = (z == 0) ? dx : (z == 1) ? d1 : (z == 2) ? d2 : (z == 3) ? d3 : d4;
  const int n4 = (z == 0) ? (NR * DM / 4) : (DM * DM / 4);
  int stride = gridDim.x * blockDim.x;
  for (int i = blockIdx.x * blockDim.x + threadIdx.x; i < n4; i += stride) {
    float4 v = ((const float4*)src)[i];
    union { bf16 h[4]; ushort4 u; } un;
    un.h[0] = __float2bfloat16(v.x);
    un.h[1] = __float2bfloat16(v.y);
    un.h[2] = __float2bfloat16(v.z);
    un.h[3] = __float2bfloat16(v.w);
    ((ushort4*)dst)[i] = un.u;
  }
}

// ---------------- QKV projection, 128x64 tiles (2-3 blocks/CU hides barrier drain) ----------
// z=0 -> Q (pre-scaled), z=1 -> K, z=2 -> V transposed
__global__ __launch_bounds__(256) void gemm_qkv_kernel(
    const bf16* __restrict__ xb,
    const bf16* __restrict__ Wqb, const bf16* __restrict__ Wkb, const bf16* __restrict__ Wvb,
    const float* __restrict__ bq, const float* __restrict__ bk, const float* __restrict__ bv,
    bf16* __restrict__ Qb, bf16* __restrict__ Kb, bf16* __restrict__ Vt) {
  __shared__ bf16 smem[8192];   // As 4096 + Bs 2048 during core; T(16KB) for V transpose
  bf16* As = smem;
  bf16* Bs = smem + 4096;
  const int z = blockIdx.z;
  const bf16* W = (z == 0) ? Wqb : (z == 1) ? Wkb : Wvb;
  const float* bias = (z == 0) ? bq : (z == 1) ? bk : bv;
  const int rowStart = blockIdx.y * 128, colStart = blockIdx.x * 64;
  const int t = threadIdx.x, lane = t & 63, w = t >> 6;
  const int lg = lane & 15, lh = lane >> 4;
  const int wm = (w >> 1) * 64, wn = (w & 1) * 32;

  f32x4 acc[4][2];
#pragma unroll
  for (int i = 0; i < 4; ++i)
#pragma unroll
    for (int j = 0; j < 2; ++j) acc[i][j] = (f32x4){0.f, 0.f, 0.f, 0.f};

  for (int kt = 0; kt < DM / 32; ++kt) {
    int kb = kt * 32;
#pragma unroll
    for (int q = 0; q < 2; ++q) {
      int idx = q * 256 + t;
      int row = idx >> 2;
      int ce = (idx & 3) * 8;
      const bf16* ga = xb + (size_t)(rowStart + row) * DM + kb + ce;
      int ldsbase = (q * 256 + w * 64) * 8;
      __builtin_amdgcn_global_load_lds((const __attribute__((address_space(1))) void*)ga,
                                       (__attribute__((address_space(3))) void*)(As + ldsbase),
                                       16, 0, 0);
    }
    {
      int row = t >> 2, ce = (t & 3) * 8;
      const bf16* gb = W + (size_t)(colStart + row) * DM + kb + ce;
      int ldsbase = (w * 64) * 8;
      __builtin_amdgcn_global_load_lds((const __attribute__((address_space(1))) void*)gb,
                                       (__attribute__((address_space(3))) void*)(Bs + ldsbase),
                                       16, 0, 0);
    }
    __syncthreads();
    bf16x8 af[4], bfr[2];
#pragma unroll
    for (int i = 0; i < 4; ++i)
      af[i] = *(const bf16x8*)(As + (wm + i * 16 + lg) * 32 + 8 * lh);
#pragma unroll
    for (int j = 0; j < 2; ++j)
      bfr[j] = *(const bf16x8*)(Bs + (wn + j * 16 + lg) * 32 + 8 * lh);
#pragma unroll
    for (int i = 0; i < 4; ++i)
#pragma unroll
      for (int j = 0; j < 2; ++j)
        acc[i][j] = __builtin_amdgcn_mfma_f32_16x16x32_bf16(af[i], bfr[j], acc[i][j], 0, 0, 0);
    __syncthreads();
  }

  if (z < 2) {
    bf16* out = (z == 0) ? Qb : Kb;
    const float sc = (z == 0) ? QSCALE : 1.0f;
#pragma unroll
    for (int i = 0; i < 4; ++i)
#pragma unroll
      for (int j = 0; j < 2; ++j) {
        int col = colStart + wn + j * 16 + lg;
        float bb = bias[col];
#pragma unroll
        for (int r = 0; r < 4; ++r) {
          int row = rowStart + wm + i * 16 + 4 * lh + r;
          out[(size_t)row * DM + col] = __float2bfloat16((acc[i][j][r] + bb) * sc);
        }
      }
  } else {
    // V: transpose via LDS [64 cols][128 rows] (swizzled), then coalesced bf16x8 stores
    char* T = (char*)smem;
    __syncthreads();
#pragma unroll
    for (int i = 0; i < 4; ++i)
#pragma unroll
      for (int j = 0; j < 2; ++j) {
        int col = wn + j * 16 + lg;     // 0..63
        float bb = bias[colStart + col];
        const int swz = (col & 7) << 4;
#pragma unroll
        for (int r2 = 0; r2 < 4; r2 += 2) {
          int row = wm + i * 16 + 4 * lh + r2;
          union { bf16 hh[2]; unsigned u; } un;
          un.hh[0] = __float2bfloat16(acc[i][j][r2] + bb);
          un.hh[1] = __float2bfloat16(acc[i][j][r2 + 1] + bb);
          *(unsigned*)(T + ((col * 256 + row * 2) ^ swz)) = un.u;
        }
      }
    __syncthreads();
    const int b_i = rowStart >> 11;
    const int sbase = rowStart & 2047;
#pragma unroll
    for (int rd = 0; rd < 4; ++rd) {
      int d_loc = rd * 16 + (t >> 4);   // 0..63
      int s8 = (t & 15) * 8;
      bf16x8 v = *(const bf16x8*)(T + ((d_loc * 256 + s8 * 2) ^ ((d_loc & 7) << 4)));
      int col = colStart + d_loc;
      int h2 = col >> 6, d = col & 63;
      *(bf16x8*)(Vt + ((size_t)(b_i * NH + h2) * DKK + d) * SL + sbase + s8) = v;
    }
  }
}

// ---------------- attention kernel A: softmax denominators only ----------------
__global__ __launch_bounds__(256) void attn_den_kernel(
    const bf16* __restrict__ Qb, const bf16* __restrict__ Kb,
    float* __restrict__ linv_g) {
  __shared__ float sl[2 * 128];
  const int t = threadIdx.x, lane = t & 63, w = t >> 6;
  const int lg = lane & 15, lh = lane >> 4;
  const int L = blockIdx.x;              // 0..511
  const int xcd = L & 7, s_in = L >> 3;
  const int bh = xcd * 4 + (s_in >> 4);
  const int qtile = s_in & 15;
  const int b = bh >> 4, h = bh & 15;
  const int qbase = qtile * 128;
  const int wr = w >> 1, wc = w & 1;

  bf16x8 qf[4][2];
#pragma unroll
  for (int i = 0; i < 4; ++i)
#pragma unroll
    for (int ks = 0; ks < 2; ++ks)
      qf[i][ks] = *(const bf16x8*)(Qb +
          (size_t)(b * SL + qbase + wr * 64 + i * 16 + lg) * DM + h * DKK + ks * 32 + 8 * lh);

  const bf16* Kbase = Kb + (size_t)b * SL * DM + h * DKK;

  float lsum[4] = {0.f, 0.f, 0.f, 0.f};
  for (int kt = 0; kt < 16; ++kt) {
    bf16x8 kf[4][2];
#pragma unroll
    for (int j = 0; j < 4; ++j)
#pragma unroll
      for (int ks = 0; ks < 2; ++ks)
        kf[j][ks] = *(const bf16x8*)(Kbase +
            (size_t)(kt * 128 + wc * 64 + j * 16 + lg) * DM + ks * 32 + 8 * lh);
#pragma unroll
    for (int i = 0; i < 4; ++i) {
      f32x4 s[4];
#pragma unroll
      for (int j = 0; j < 4; ++j) {
        f32x4 z = (f32x4){0.f, 0.f, 0.f, 0.f};
        z = __builtin_amdgcn_mfma_f32_16x16x32_bf16(kf[j][0], qf[i][0], z, 0, 0, 0);
        s[j] = __builtin_amdgcn_mfma_f32_16x16x32_bf16(kf[j][1], qf[i][1], z, 0, 0, 0);
      }
#pragma unroll
      for (int j = 0; j < 4; ++j)
#pragma unroll
        for (int r = 0; r < 4; ++r) lsum[i] += exp2f(s[j][r]);
    }
  }
#pragma unroll
  for (int i = 0; i < 4; ++i) {
    lsum[i] += __shfl_xor(lsum[i], 16);
    lsum[i] += __shfl_xor(lsum[i], 32);
  }
  if (lh == 0) {
#pragma unroll
    for (int i = 0; i < 4; ++i) sl[wc * 128 + wr * 64 + i * 16 + lg] = lsum[i];
  }
  __syncthreads();
  if (t < 128) {
    linv_g[(size_t)bh * SL + qbase + t] = 1.f / (sl[t] + sl[128 + t]);
  }
}

// ---------------- attention kernel B: r11 structure (NT stores, load-early) ----------------
__global__ __launch_bounds__(256) void attn_wr_kernel(
    const bf16* __restrict__ Qb, const bf16* __restrict__ Kb, const bf16* __restrict__ Vt,
    const float* __restrict__ linv_g,
    float* __restrict__ attn_out, bf16* __restrict__ ctxb) {
  __shared__ bf16 Ps[4][2][32 * 128];  // [wave][buf][q][key] = 64 KB total
  const int t = threadIdx.x, lane = t & 63, w = t >> 6;
  const int lg = lane & 15, lh = lane >> 4;
  const int L = blockIdx.x;              // 0..511
  const int xcd = L & 7, s_in = L >> 3;
  const int bh = xcd * 4 + (s_in >> 4);
  const int qtile = s_in & 15;
  const int b = bh >> 4, h = bh & 15;
  const int qb2 = qtile * 128 + w * 32;  // this wave's 32 q-rows
  char* Pw = (char*)(&Ps[w][0][0]);

  bf16x8 qf[2][2];
#pragma unroll
  for (int i = 0; i < 2; ++i)
#pragma unroll
    for (int ks = 0; ks < 2; ++ks)
      qf[i][ks] = *(const bf16x8*)(Qb +
          (size_t)(b * SL + qb2 + i * 16 + lg) * DM + h * DKK + ks * 32 + 8 * lh);

  float linv[2];
#pragma unroll
  for (int i = 0; i < 2; ++i)
    linv[i] = linv_g[(size_t)bh * SL + qb2 + i * 16 + lg];

  const bf16* Kbase = Kb + (size_t)b * SL * DM + h * DKK;
  const bf16* Vtb = Vt + (size_t)bh * DKK * SL;
  float* attn_base = attn_out + (size_t)bh * SL * SL;

  f32x4 cacc[2][4];
#pragma unroll
  for (int i = 0; i < 2; ++i)
#pragma unroll
    for (int jd = 0; jd < 4; ++jd) cacc[i][jd] = (f32x4){0.f, 0.f, 0.f, 0.f};

  for (int kt = 0; kt < 16; ++kt) {
    char* Pb = Pw + (kt & 1) * 8192;
    // --- all global loads for this kt issued FIRST (older than this kt's stores) ---
    bf16x8 kf[8][2];
#pragma unroll
    for (int j = 0; j < 8; ++j)
#pragma unroll
      for (int ks = 0; ks < 2; ++ks)
        kf[j][ks] = *(const bf16x8*)(Kbase +
            (size_t)(kt * 128 + j * 16 + lg) * DM + ks * 32 + 8 * lh);
    bf16x8 vfall[4][4];
#pragma unroll
    for (int ks = 0; ks < 4; ++ks)
#pragma unroll
      for (int jd = 0; jd < 4; ++jd)
        vfall[ks][jd] = *(const bf16x8*)(Vtb +
            (size_t)(jd * 16 + lg) * SL + kt * 128 + ks * 32 + 8 * lh);

    // --- QK^T + exp2 -> normalized P: NT scatter store + LDS write ---
#pragma unroll
    for (int i = 0; i < 2; ++i) {
      f32x4 s[8];
      __builtin_amdgcn_s_setprio(1);
#pragma unroll
      for (int j = 0; j < 8; ++j) {
        f32x4 z = (f32x4){0.f, 0.f, 0.f, 0.f};
        z = __builtin_amdgcn_mfma_f32_16x16x32_bf16(kf[j][0], qf[i][0], z, 0, 0, 0);
        s[j] = __builtin_amdgcn_mfma_f32_16x16x32_bf16(kf[j][1], qf[i][1], z, 0, 0, 0);
      }
      __builtin_amdgcn_s_setprio(0);
      const int qloc = i * 16 + lg;
      const int swz = (qloc & 7) << 4;
#pragma unroll
      for (int j = 0; j < 8; ++j) {
        const int key0 = j * 16 + 4 * lh;
        f32x4 p4;
        p4[0] = exp2f(s[j][0]) * linv[i];
        p4[1] = exp2f(s[j][1]) * linv[i];
        p4[2] = exp2f(s[j][2]) * linv[i];
        p4[3] = exp2f(s[j][3]) * linv[i];
        __builtin_nontemporal_store(p4,
            (f32x4*)(attn_base + (size_t)(qb2 + qloc) * SL + kt * 128 + key0));
        union { bf16 hh[4]; ushort4 u4; } un;
        un.hh[0] = __float2bfloat16(p4[0]);
        un.hh[1] = __float2bfloat16(p4[1]);
        un.hh[2] = __float2bfloat16(p4[2]);
        un.hh[3] = __float2bfloat16(p4[3]);
        *(ushort4*)(Pb + ((qloc * 256 + key0 * 2) ^ swz)) = un.u4;
      }
    }

    // --- PV: P from LDS, V already in regs (wait on V leaves stores in flight) ---
    __builtin_amdgcn_s_setprio(1);
#pragma unroll
    for (int ks = 0; ks < 4; ++ks) {
      bf16x8 pf[2];
#pragma unroll
      for (int i = 0; i < 2; ++i) {
        const int qloc = i * 16 + lg;
        pf[i] = *(const bf16x8*)(Pb + ((qloc * 256 + (ks * 32 + 8 * lh) * 2) ^ ((qloc & 7) << 4)));
      }
#pragma unroll
      for (int i = 0; i < 2; ++i)
#pragma unroll
        for (int jd = 0; jd < 4; ++jd)
          cacc[i][jd] = __builtin_amdgcn_mfma_f32_16x16x32_bf16(pf[i], vfall[ks][jd], cacc[i][jd], 0, 0, 0);
    }
    __builtin_amdgcn_s_setprio(0);
  }

  // ctx (already normalized) -> [B*S, DM] bf16
#pragma unroll
  for (int i = 0; i < 2; ++i)
#pragma unroll
    for (int jd = 0; jd < 4; ++jd)
#pragma unroll
      for (int r = 0; r < 4; ++r) {
        int row = qb2 + i * 16 + 4 * lh + r;
        int d = jd * 16 + lg;
        ctxb[(size_t)(b * SL + row) * DM + h * DKK + d] = __float2bfloat16(cacc[i][jd][r]);
      }
}

// ---------------- O projection + bias + residual (128x64 tiles) ----------------
__global__ __launch_bounds__(256) void gemm_o_kernel(
    const bf16* __restrict__ ctxb, const bf16* __restrict__ Wob, const float* __restrict__ bo,
    const float* __restrict__ xf, float* __restrict__ ypre) {
  __shared__ bf16 As[128 * 32], Bs[64 * 32];
  const int t = threadIdx.x, lane = t & 63, w = t >> 6;
  const int lg = lane & 15, lh = lane >> 4;
  const int wm = (w >> 1) * 64, wn = (w & 1) * 32;
  int rowStart = blockIdx.y * 128, colStart = blockIdx.x * 64;
  f32x4 acc[4][2];
#pragma unroll
  for (int i = 0; i < 4; ++i)
#pragma unroll
    for (int j = 0; j < 2; ++j) acc[i][j] = (f32x4){0.f, 0.f, 0.f, 0.f};

  for (int kt = 0; kt < DM / 32; ++kt) {
    int kb = kt * 32;
#pragma unroll
    for (int q = 0; q < 2; ++q) {
      int idx = q * 256 + t;
      int row = idx >> 2;
      int ce = (idx & 3) * 8;
      const bf16* ga = ctxb + (size_t)(rowStart + row) * DM + kb + ce;
      int ldsbase = (q * 256 + w * 64) * 8;
      __builtin_amdgcn_global_load_lds((const __attribute__((address_space(1))) void*)ga,
                                       (__attribute__((address_space(3))) void*)(As + ldsbase),
                                       16, 0, 0);
    }
    {
      int row = t >> 2, ce = (t & 3) * 8;
      const bf16* gb = Wob + (size_t)(colStart + row) * DM + kb + ce;
      int ldsbase = (w * 64) * 8;
      __builtin_amdgcn_global_load_lds((const __attribute__((address_space(1))) void*)gb,
                                       (__attribute__((address_space(3))) void*)(Bs + ldsbase),
                                       16, 0, 0);
    }
    __syncthreads();
    bf16x8 af[4], bfr[2];
#pragma unroll
    for (int i = 0; i < 4; ++i)
      af[i] = *(const bf16x8*)(As + (wm + i * 16 + lg) * 32 + 8 * lh);
#pragma unroll
    for (int j = 0; j < 2; ++j)
      bfr[j] = *(const bf16x8*)(Bs + (wn + j * 16 + lg) * 32 + 8 * lh);
#pragma unroll
    for (int i = 0; i < 4; ++i)
#pragma unroll
      for (int j = 0; j < 2; ++j)
        acc[i][j] = __builtin_amdgcn_mfma_f32_16x16x32_bf16(af[i], bfr[j], acc[i][j], 0, 0, 0);
    __syncthreads();
  }
#pragma unroll
  for (int i = 0; i < 4; ++i)
#pragma unroll
    for (int j = 0; j < 2; ++j) {
      int col = colStart + wn + j * 16 + lg;
      float bb = bo[col];
#pragma unroll
      for (int r = 0; r < 4; ++r) {
        int row = rowStart + wm + i * 16 + 4 * lh + r;
        ypre[(size_t)row * DM + col] = acc[i][j][r] + bb + xf[(size_t)row * DM + col];
      }
    }
}

// ---------------- row LayerNorm ----------------
__global__ __launch_bounds__(256) void ln_kernel(const float* __restrict__ ypre,
                                                 const float* __restrict__ g,
                                                 const float* __restrict__ bta,
                                                 float* __restrict__ out) {
  int row = blockIdx.x;
  const float* yr = ypre + (size_t)row * DM;
  int t = threadIdx.x;
  float4 v = *(const float4*)(yr + t * 4);
  float s = v.x + v.y + v.z + v.w;
  float ss = v.x * v.x + v.y * v.y + v.z * v.z + v.w * v.w;
#pragma unroll
  for (int off = 1; off < 64; off <<= 1) {
    s += __shfl_xor(s, off);
    ss += __shfl_xor(ss, off);
  }
  __shared__ float red[8];
  int w = t >> 6, lane = t & 63;
  if (lane == 0) { red[w] = s; red[4 + w] = ss; }
  __syncthreads();
  s = red[0] + red[1] + red[2] + red[3];
  ss = red[4] + red[5] + red[6] + red[7];
  float mu = s * (1.f / (float)DM);
  float var = ss * (1.f / (float)DM) - mu * mu;
  float rstd = rsqrtf(var + 1e-5f);
  float4 gv = *(const float4*)(g + t * 4);
  float4 bv = *(const float4*)(bta + t * 4);
  float4 o;
  o.x = (v.x - mu) * rstd * gv.x + bv.x;
  o.y = (v.y - mu) * rstd * gv.y + bv.y;
  o.z = (v.z - mu) * rstd * gv.z + bv.z;
  o.w = (v.w - mu) * rstd * gv.w + bv.w;
  *(float4*)(out + (size_t)row * DM + t * 4) = o;
}

extern "C" void kernel_launch(void* const* d_in, const int* in_sizes, int n_in,
                              void* d_out, int out_size, void* d_ws, size_t ws_size,
                              hipStream_t stream) {
  (void)in_sizes; (void)n_in; (void)out_size; (void)ws_size;
  const float* x = (const float*)d_in[0];
  // d_in[1] (reasoning_state), d_in[8] (Wr), d_in[9] (br): softmax-shift-invariant, unused
  const float* Wq = (const float*)d_in[2];
  const float* bq = (const float*)d_in[3];
  const float* Wk = (const float*)d_in[4];
  const float* bk = (const float*)d_in[5];
  const float* Wv = (const float*)d_in[6];
  const float* bv = (const float*)d_in[7];
  const float* Wo = (const float*)d_in[10];
  const float* bo = (const float*)d_in[11];
  const float* ln_g = (const float*)d_in[12];
  const float* ln_b = (const float*)d_in[13];
  float* out = (float*)d_out;

  char* ws = (char*)d_ws;
  const size_t MB = 1ull << 20;
  bf16* xb   = (bf16*)(ws + 0 * MB);    // 8 MB
  bf16* Wqb  = (bf16*)(ws + 8 * MB);    // 2 MB
  bf16* Wkb  = (bf16*)(ws + 10 * MB);   // 2 MB
  bf16* Wvb  = (bf16*)(ws + 12 * MB);   // 2 MB
  bf16* Wob  = (bf16*)(ws + 14 * MB);   // 2 MB
  bf16* Qb   = (bf16*)(ws + 16 * MB);   // 8 MB (pre-scaled by QSCALE)
  bf16* Kb   = (bf16*)(ws + 24 * MB);   // 8 MB
  bf16* Vt   = (bf16*)(ws + 32 * MB);   // 8 MB, [B,H,dk,S]
  bf16* ctxb = (bf16*)(ws + 40 * MB);   // 8 MB
  float* ypre = (float*)(ws + 48 * MB); // 16 MB
  float* linv_g = (float*)(ws + 64 * MB); // 256 KB

  float* y_out = out;                       // 4 M floats
  float* attn_out = out + (size_t)NR * DM;  // 134 M floats

  cvt5_kernel<<<dim3(512, 5), 256, 0, stream>>>(x, Wq, Wk, Wv, Wo, xb, Wqb, Wkb, Wvb, Wob);

  gemm_qkv_kernel<<<dim3(16, 32, 3), 256, 0, stream>>>(xb, Wqb, Wkb, Wvb, bq, bk, bv, Qb, Kb, Vt);
  attn_den_kernel<<<512, 256, 0, stream>>>(Qb, Kb, linv_g);
  attn_wr_kernel<<<512, 256, 0, stream>>>(Qb, Kb, Vt, linv_g, attn_out, ctxb);
  gemm_o_kernel<<<dim3(16, 32), 256, 0, stream>>>(ctxb, Wob, bo, x, ypre);
  ln_kernel<<<4096, 256, 0, stream>>>(ypre, ln_g, ln_b, y_out);
}